// Round 2
// baseline (376.489 us; speedup 1.0000x reference)
//
#include <hip/hip_runtime.h>
#include <hip/hip_bf16.h>
#include <stdint.h>

#define B_   4
#define S_   1024
#define H_   1024      // hidden
#define NH_  16        // ENT
#define D_   64        // INNER
#define N1_  2048      // ENT*2*INNER
#define M1_  4096      // B*S
#define NEG_ 1000000000000.0f

typedef __attribute__((ext_vector_type(8))) short bf16x8;
typedef __attribute__((ext_vector_type(4))) float f32x4;

__device__ inline void gload_lds16(const void* g, void* l) {
  __builtin_amdgcn_global_load_lds(
      (const __attribute__((address_space(1))) unsigned int*)g,
      (__attribute__((address_space(3))) unsigned int*)l, 16, 0, 0);
}

__device__ inline unsigned short f2bf(float f) {
  union { float f; uint32_t u; } a; a.f = f;
  uint32_t r = a.u + 0x7fff + ((a.u >> 16) & 1);   // RNE
  return (unsigned short)(r >> 16);
}

// ---------------- prep kernels ----------------

__global__ void k_cast(const float4* __restrict__ in, unsigned short* __restrict__ out, int n4) {
  int i = blockIdx.x * 256 + threadIdx.x;
  if (i >= n4) return;
  float4 v = in[i];
  uint64_t pk = (uint64_t)f2bf(v.x) | ((uint64_t)f2bf(v.y) << 16) |
                ((uint64_t)f2bf(v.z) << 32) | ((uint64_t)f2bf(v.w) << 48);
  ((uint64_t*)out)[i] = pk;
}

// W (H_ x N1_) fp32 -> WT (N1_ x H_) bf16
__global__ void k_transW(const float* __restrict__ W, unsigned short* __restrict__ WT) {
  __shared__ float t[32][33];
  int nb = blockIdx.x * 32, kb = blockIdx.y * 32;
  int tx = threadIdx.x, ty = threadIdx.y;   // (32, 8)
  for (int r = 0; r < 4; r++)
    t[ty + r * 8][tx] = W[(size_t)(kb + ty + r * 8) * N1_ + nb + tx];
  __syncthreads();
  for (int r = 0; r < 4; r++)
    WT[(size_t)(nb + ty + r * 8) * H_ + kb + tx] = f2bf(t[tx][ty + r * 8]);
}

// sin/cos table: tab[(pos*32+fi)*2] = sin, +1 = cos
__global__ void k_sincos(float* __restrict__ tab) {
  int i = blockIdx.x * 256 + threadIdx.x;  // 0..32767
  if (i >= S_ * 32) return;
  int pos = i >> 5, fi = i & 31;
  float freq = exp2f(-(float)fi * (13.2877123795494f / 32.0f)); // 10000^(-2fi/64)
  float ang = (float)pos * freq;
  tab[2 * i]     = sinf(ang);
  tab[2 * i + 1] = cosf(ang);
}

// ---------------- stage 1: P = lhs @ W + b, fused RoPE, scatter to q/k ----------------
// Operand-swapped MFMA: acc[j][i] = mfma(bf[j], af[i], .) puts n in the register
// axis (4 consecutive n per lane) -> in-lane RoPE pairs, vector epilogue.

__global__ __launch_bounds__(256) void k_gemm1(
    const unsigned short* __restrict__ A,   // M1_ x H_ bf16
    const unsigned short* __restrict__ BT,  // N1_ x H_ bf16
    const float* __restrict__ bias,         // N1_
    const float* __restrict__ sc,           // sin/cos table
    unsigned short* __restrict__ qws,       // [B*NH][S][D] bf16
    unsigned short* __restrict__ kws) {
  __shared__ unsigned short a_lds[128 * 32];
  __shared__ unsigned short b_lds[128 * 32];
  int t = threadIdx.x;
  int lane = t & 63, wv = t >> 6;
  int wm = wv >> 1, wn = wv & 1;
  int col = lane & 15, quad = lane >> 4;
  int mBase = blockIdx.y * 128, nBase = blockIdx.x * 128;

  f32x4 acc[4][4] = {};   // [j: n-tile][i: m-tile]

  for (int kk = 0; kk < H_; kk += 32) {
    for (int c = 0; c < 2; c++) {
      int idx = c * 256 + t;
      int r = idx >> 2, ch = idx & 3;
      gload_lds16(A + (size_t)(mBase + r) * H_ + kk + ch * 8, a_lds + idx * 8);
      gload_lds16(BT + (size_t)(nBase + r) * H_ + kk + ch * 8, b_lds + idx * 8);
    }
    __syncthreads();
    bf16x8 af[4], bf[4];
#pragma unroll
    for (int i = 0; i < 4; i++)
      af[i] = *(const bf16x8*)&a_lds[(wm * 64 + i * 16 + col) * 32 + quad * 8];
#pragma unroll
    for (int j = 0; j < 4; j++)
      bf[j] = *(const bf16x8*)&b_lds[(wn * 64 + j * 16 + col) * 32 + quad * 8];
#pragma unroll
    for (int j = 0; j < 4; j++)
#pragma unroll
      for (int i = 0; i < 4; i++)
        acc[j][i] = __builtin_amdgcn_mfma_f32_16x16x32_bf16(bf[j], af[i], acc[j][i], 0, 0, 0);
    __syncthreads();
  }

  // epilogue: bias + interleaved RoPE (pairs in-lane) + ushort4 scatter
#pragma unroll
  for (int i = 0; i < 4; i++) {
    int m = mBase + wm * 64 + i * 16 + col;      // 0..4095
    int pos = m & (S_ - 1);
    int bb = m >> 10;
#pragma unroll
    for (int j = 0; j < 4; j++) {
      int n = nBase + wn * 64 + j * 16 + quad * 4;  // 4-aligned
      int d = n & 63;
      int head = n >> 7;
      int isK = (n >> 6) & 1;
      float4 bj  = *(const float4*)&bias[n];
      float4 scv = *(const float4*)&sc[(pos * 32 + (d >> 1)) * 2]; // s0,c0,s1,c1
      float v0 = acc[j][i][0] + bj.x;
      float v1 = acc[j][i][1] + bj.y;
      float v2 = acc[j][i][2] + bj.z;
      float v3 = acc[j][i][3] + bj.w;
      float o0 = v0 * scv.y - v1 * scv.x;
      float o1 = v1 * scv.y + v0 * scv.x;
      float o2 = v2 * scv.w - v3 * scv.z;
      float o3 = v3 * scv.w + v2 * scv.z;
      unsigned short* dst = isK ? kws : qws;
      ushort4 pk;
      pk.x = f2bf(o0); pk.y = f2bf(o1); pk.z = f2bf(o2); pk.w = f2bf(o3);
      *(ushort4*)&dst[((size_t)(bb * NH_ + head) * S_ + pos) * D_ + d] = pk;
    }
  }
}

// ---------------- stage 2: logits[b,h] = Q K^T with masks ----------------
// Operand-swapped: n in register axis -> float4 output stores.

__global__ __launch_bounds__(256) void k_gemm2(
    const unsigned short* __restrict__ qws,
    const unsigned short* __restrict__ kws,
    const float* __restrict__ tl,           // (B, S)
    float* __restrict__ out) {
  __shared__ unsigned short q_lds[128 * 64];
  __shared__ unsigned short k_lds[128 * 64];
  int t = threadIdx.x;
  int lane = t & 63, wv = t >> 6, wm = wv >> 1, wn = wv & 1;
  int col = lane & 15, quad = lane >> 4;
  int z = blockIdx.z;                       // b*16+h
  int mT = blockIdx.y * 128, nT = blockIdx.x * 128;
  const unsigned short* qb = qws + ((size_t)z * S_ + mT) * D_;  // contiguous 16KB
  const unsigned short* kb = kws + ((size_t)z * S_ + nT) * D_;

  for (int c = 0; c < 4; c++) {
    int idx = c * 256 + t;
    gload_lds16(qb + idx * 8, q_lds + idx * 8);
    gload_lds16(kb + idx * 8, k_lds + idx * 8);
  }
  __syncthreads();

  f32x4 acc[4][4] = {};   // [j: n-tile][i: m-tile]
#pragma unroll
  for (int kk = 0; kk < 64; kk += 32) {
    bf16x8 qf[4], kf[4];
#pragma unroll
    for (int i = 0; i < 4; i++)
      qf[i] = *(const bf16x8*)&q_lds[(wm * 64 + i * 16 + col) * 64 + kk + quad * 8];
#pragma unroll
    for (int j = 0; j < 4; j++)
      kf[j] = *(const bf16x8*)&k_lds[(wn * 64 + j * 16 + col) * 64 + kk + quad * 8];
#pragma unroll
    for (int j = 0; j < 4; j++)
#pragma unroll
      for (int i = 0; i < 4; i++)
        acc[j][i] = __builtin_amdgcn_mfma_f32_16x16x32_bf16(kf[j], qf[i], acc[j][i], 0, 0, 0);
  }

  int bb = z >> 4;
#pragma unroll
  for (int i = 0; i < 4; i++) {
    int m = mT + wm * 64 + i * 16 + col;
    float* orow = out + ((size_t)z * S_ + m) * S_;
#pragma unroll
    for (int j = 0; j < 4; j++) {
      int n = nT + wn * 64 + j * 16 + quad * 4;   // 4-aligned
      float4 pad4 = *(const float4*)&tl[bb * S_ + n];
      float4 r;
      float v;
      v = acc[j][i][0] * pad4.x - (1.0f - pad4.x) * NEG_; if (m > n)     v -= NEG_; r.x = v * 0.125f;
      v = acc[j][i][1] * pad4.y - (1.0f - pad4.y) * NEG_; if (m > n + 1) v -= NEG_; r.y = v * 0.125f;
      v = acc[j][i][2] * pad4.z - (1.0f - pad4.z) * NEG_; if (m > n + 2) v -= NEG_; r.z = v * 0.125f;
      v = acc[j][i][3] * pad4.w - (1.0f - pad4.w) * NEG_; if (m > n + 3) v -= NEG_; r.w = v * 0.125f;
      *(float4*)&orow[n] = r;
    }
  }
}

// ---------------- launch ----------------

extern "C" void kernel_launch(void* const* d_in, const int* in_sizes, int n_in,
                              void* d_out, int out_size, void* d_ws, size_t ws_size,
                              hipStream_t stream) {
  const float* lhs  = (const float*)d_in[0];   // (4,1024,1024)
  const float* W    = (const float*)d_in[1];   // (1024,2048)
  const float* bias = (const float*)d_in[2];   // (2048,)
  const float* tl   = (const float*)d_in[3];   // (4,1024)
  float* out = (float*)d_out;

  char* ws = (char*)d_ws;
  unsigned short* lhsb = (unsigned short*)(ws);                      // 8 MB
  unsigned short* WT   = (unsigned short*)(ws + (8u  << 20));        // 4 MB
  unsigned short* qws  = (unsigned short*)(ws + (12u << 20));        // 8 MB
  unsigned short* kws  = (unsigned short*)(ws + (20u << 20));        // 8 MB
  float*          sc   = (float*)        (ws + (28u << 20));         // 256 KB

  k_cast<<<(M1_ * H_ / 4 + 255) / 256, 256, 0, stream>>>((const float4*)lhs, lhsb, M1_ * H_ / 4);
  k_transW<<<dim3(N1_ / 32, H_ / 32), dim3(32, 8), 0, stream>>>(W, WT);
  k_sincos<<<(S_ * 32 + 255) / 256, 256, 0, stream>>>(sc);
  k_gemm1<<<dim3(N1_ / 128, M1_ / 128), 256, 0, stream>>>(lhsb, WT, bias, sc, qws, kws);
  k_gemm2<<<dim3(S_ / 128, S_ / 128, B_ * NH_), 256, 0, stream>>>(qws, kws, tl, out);
}

// Round 3
// 341.084 us; speedup vs baseline: 1.1038x; 1.1038x over previous
//
#include <hip/hip_runtime.h>
#include <hip/hip_bf16.h>
#include <stdint.h>

#define B_   4
#define S_   1024
#define H_   1024      // hidden
#define NH_  16        // ENT
#define D_   64        // INNER
#define N1_  2048      // ENT*2*INNER
#define M1_  4096      // B*S
#define NEG_ 1000000000000.0f

typedef __attribute__((ext_vector_type(8))) short bf16x8;
typedef __attribute__((ext_vector_type(4))) float f32x4;

__device__ inline void gload_lds16(const void* g, void* l) {
  __builtin_amdgcn_global_load_lds(
      (const __attribute__((address_space(1))) unsigned int*)g,
      (__attribute__((address_space(3))) unsigned int*)l, 16, 0, 0);
}

__device__ inline unsigned short f2bf(float f) {
  union { float f; uint32_t u; } a; a.f = f;
  uint32_t r = a.u + 0x7fff + ((a.u >> 16) & 1);   // RNE
  return (unsigned short)(r >> 16);
}

// ---------------- prep kernels ----------------

__global__ void k_cast(const float4* __restrict__ in, unsigned short* __restrict__ out, int n4) {
  int i = blockIdx.x * 256 + threadIdx.x;
  if (i >= n4) return;
  float4 v = in[i];
  uint64_t pk = (uint64_t)f2bf(v.x) | ((uint64_t)f2bf(v.y) << 16) |
                ((uint64_t)f2bf(v.z) << 32) | ((uint64_t)f2bf(v.w) << 48);
  ((uint64_t*)out)[i] = pk;
}

// W (H_ x N1_) fp32 -> WT (N1_ x H_) bf16
__global__ void k_transW(const float* __restrict__ W, unsigned short* __restrict__ WT) {
  __shared__ float t[32][33];
  int nb = blockIdx.x * 32, kb = blockIdx.y * 32;
  int tx = threadIdx.x, ty = threadIdx.y;   // (32, 8)
  for (int r = 0; r < 4; r++)
    t[ty + r * 8][tx] = W[(size_t)(kb + ty + r * 8) * N1_ + nb + tx];
  __syncthreads();
  for (int r = 0; r < 4; r++)
    WT[(size_t)(nb + ty + r * 8) * H_ + kb + tx] = f2bf(t[tx][ty + r * 8]);
}

// sin/cos table: tab[(pos*32+fi)*2] = sin, +1 = cos
__global__ void k_sincos(float* __restrict__ tab) {
  int i = blockIdx.x * 256 + threadIdx.x;  // 0..32767
  if (i >= S_ * 32) return;
  int pos = i >> 5, fi = i & 31;
  float freq = exp2f(-(float)fi * (13.2877123795494f / 32.0f)); // 10000^(-2fi/64)
  float ang = (float)pos * freq;
  tab[2 * i]     = sinf(ang);
  tab[2 * i + 1] = cosf(ang);
}

// ---------------- stage 1: P = lhs @ W + b, fused RoPE, scatter to q/k ----------------
// Operand-swapped MFMA: acc[j][i] = mfma(bf[j], af[i], .) puts n in the register
// axis (4 consecutive n per lane) -> in-lane RoPE pairs, vector epilogue.

__global__ __launch_bounds__(256) void k_gemm1(
    const unsigned short* __restrict__ A,   // M1_ x H_ bf16
    const unsigned short* __restrict__ BT,  // N1_ x H_ bf16
    const float* __restrict__ bias,         // N1_
    const float* __restrict__ sc,           // sin/cos table
    unsigned short* __restrict__ qws,       // [B*NH][S][D] bf16
    unsigned short* __restrict__ kws) {
  __shared__ unsigned short a_lds[128 * 32];
  __shared__ unsigned short b_lds[128 * 32];
  int t = threadIdx.x;
  int lane = t & 63, wv = t >> 6;
  int wm = wv >> 1, wn = wv & 1;
  int col = lane & 15, quad = lane >> 4;
  int mBase = blockIdx.y * 128, nBase = blockIdx.x * 128;

  f32x4 acc[4][4] = {};   // [j: n-tile][i: m-tile]

  for (int kk = 0; kk < H_; kk += 32) {
    for (int c = 0; c < 2; c++) {
      int idx = c * 256 + t;
      int r = idx >> 2, ch = idx & 3;
      gload_lds16(A + (size_t)(mBase + r) * H_ + kk + ch * 8, a_lds + idx * 8);
      gload_lds16(BT + (size_t)(nBase + r) * H_ + kk + ch * 8, b_lds + idx * 8);
    }
    __syncthreads();
    bf16x8 af[4], bf[4];
#pragma unroll
    for (int i = 0; i < 4; i++)
      af[i] = *(const bf16x8*)&a_lds[(wm * 64 + i * 16 + col) * 32 + quad * 8];
#pragma unroll
    for (int j = 0; j < 4; j++)
      bf[j] = *(const bf16x8*)&b_lds[(wn * 64 + j * 16 + col) * 32 + quad * 8];
#pragma unroll
    for (int j = 0; j < 4; j++)
#pragma unroll
      for (int i = 0; i < 4; i++)
        acc[j][i] = __builtin_amdgcn_mfma_f32_16x16x32_bf16(bf[j], af[i], acc[j][i], 0, 0, 0);
    __syncthreads();
  }

  // epilogue: bias + interleaved RoPE (pairs in-lane) + ushort4 scatter
#pragma unroll
  for (int i = 0; i < 4; i++) {
    int m = mBase + wm * 64 + i * 16 + col;      // 0..4095
    int pos = m & (S_ - 1);
    int bb = m >> 10;
#pragma unroll
    for (int j = 0; j < 4; j++) {
      int n = nBase + wn * 64 + j * 16 + quad * 4;  // 4-aligned
      int d = n & 63;
      int head = n >> 7;
      int isK = (n >> 6) & 1;
      float4 bj  = *(const float4*)&bias[n];
      float4 scv = *(const float4*)&sc[(pos * 32 + (d >> 1)) * 2]; // s0,c0,s1,c1
      float v0 = acc[j][i][0] + bj.x;
      float v1 = acc[j][i][1] + bj.y;
      float v2 = acc[j][i][2] + bj.z;
      float v3 = acc[j][i][3] + bj.w;
      float o0 = v0 * scv.y - v1 * scv.x;
      float o1 = v1 * scv.y + v0 * scv.x;
      float o2 = v2 * scv.w - v3 * scv.z;
      float o3 = v3 * scv.w + v2 * scv.z;
      unsigned short* dst = isK ? kws : qws;
      ushort4 pk;
      pk.x = f2bf(o0); pk.y = f2bf(o1); pk.z = f2bf(o2); pk.w = f2bf(o3);
      *(ushort4*)&dst[((size_t)(bb * NH_ + head) * S_ + pos) * D_ + d] = pk;
    }
  }
}

// ---------------- stage 2: logits[b,h] = Q K^T with masks ----------------
// Operand-swapped MFMA + LDS-transposed epilogue for fully coalesced stores.

#define STG_ 132   // stage row stride in floats (pad 4: float4-aligned, spreads banks)

__global__ __launch_bounds__(256) void k_gemm2(
    const unsigned short* __restrict__ qws,
    const unsigned short* __restrict__ kws,
    const float* __restrict__ tl,           // (B, S)
    float* __restrict__ out) {
  __shared__ __align__(16) char smem[64 * STG_ * 4];   // 33792 B >= 32768 B
  unsigned short* q_lds = (unsigned short*)smem;
  unsigned short* k_lds = q_lds + 128 * 64;
  float* stage = (float*)smem;

  int t = threadIdx.x;
  int lane = t & 63, wv = t >> 6, wm = wv >> 1, wn = wv & 1;
  int col = lane & 15, quad = lane >> 4;
  int z = blockIdx.z;                       // b*16+h
  int mT = blockIdx.y * 128, nT = blockIdx.x * 128;
  const unsigned short* qb = qws + ((size_t)z * S_ + mT) * D_;  // contiguous 16KB
  const unsigned short* kb = kws + ((size_t)z * S_ + nT) * D_;

  for (int c = 0; c < 4; c++) {
    int idx = c * 256 + t;
    gload_lds16(qb + idx * 8, q_lds + idx * 8);
    gload_lds16(kb + idx * 8, k_lds + idx * 8);
  }
  __syncthreads();

  f32x4 acc[4][4] = {};   // [j: n-tile][i: m-tile]
#pragma unroll
  for (int kk = 0; kk < 64; kk += 32) {
    bf16x8 qf[4], kf[4];
#pragma unroll
    for (int i = 0; i < 4; i++)
      qf[i] = *(const bf16x8*)&q_lds[(wm * 64 + i * 16 + col) * 64 + kk + quad * 8];
#pragma unroll
    for (int j = 0; j < 4; j++)
      kf[j] = *(const bf16x8*)&k_lds[(wn * 64 + j * 16 + col) * 64 + kk + quad * 8];
#pragma unroll
    for (int j = 0; j < 4; j++)
#pragma unroll
      for (int i = 0; i < 4; i++)
        acc[j][i] = __builtin_amdgcn_mfma_f32_16x16x32_bf16(kf[j], qf[i], acc[j][i], 0, 0, 0);
  }
  __syncthreads();   // everyone done reading q_lds/k_lds before stage overwrite

  int bb = z >> 4;
#pragma unroll
  for (int half = 0; half < 2; half++) {
    if (wm == half) {
      // my acc rows are local rows 0..63 of this half
#pragma unroll
      for (int i = 0; i < 4; i++) {
        int rloc = i * 16 + col;
#pragma unroll
        for (int j = 0; j < 4; j++) {
          int cloc = wn * 64 + j * 16 + quad * 4;
          float4 v;
          v.x = acc[j][i][0]; v.y = acc[j][i][1];
          v.z = acc[j][i][2]; v.w = acc[j][i][3];
          *(float4*)&stage[rloc * STG_ + cloc] = v;
        }
      }
    }
    __syncthreads();
    // all 256 threads: store 64 rows x 128 cols, fully coalesced
    int mbase = mT + half * 64;
#pragma unroll
    for (int r = 0; r < 8; r++) {
      int f = r * 256 + t;        // 0..2047
      int rloc = f >> 5;          // 0..63
      int c4 = (f & 31) * 4;      // 0..124
      float4 v = *(const float4*)&stage[rloc * STG_ + c4];
      int m = mbase + rloc;
      int n = nT + c4;
      float4 pad4 = *(const float4*)&tl[bb * S_ + n];
      float4 o;
      float x;
      x = v.x * pad4.x - (1.0f - pad4.x) * NEG_; if (m > n)     x -= NEG_; o.x = x * 0.125f;
      x = v.y * pad4.y - (1.0f - pad4.y) * NEG_; if (m > n + 1) x -= NEG_; o.y = x * 0.125f;
      x = v.z * pad4.z - (1.0f - pad4.z) * NEG_; if (m > n + 2) x -= NEG_; o.z = x * 0.125f;
      x = v.w * pad4.w - (1.0f - pad4.w) * NEG_; if (m > n + 3) x -= NEG_; o.w = x * 0.125f;
      *(float4*)&out[((size_t)z * S_ + m) * S_ + n] = o;
    }
    __syncthreads();   // protect stage before next half's writes
  }
}

// ---------------- launch ----------------

extern "C" void kernel_launch(void* const* d_in, const int* in_sizes, int n_in,
                              void* d_out, int out_size, void* d_ws, size_t ws_size,
                              hipStream_t stream) {
  const float* lhs  = (const float*)d_in[0];   // (4,1024,1024)
  const float* W    = (const float*)d_in[1];   // (1024,2048)
  const float* bias = (const float*)d_in[2];   // (2048,)
  const float* tl   = (const float*)d_in[3];   // (4,1024)
  float* out = (float*)d_out;

  char* ws = (char*)d_ws;
  unsigned short* lhsb = (unsigned short*)(ws);                      // 8 MB
  unsigned short* WT   = (unsigned short*)(ws + (8u  << 20));        // 4 MB
  unsigned short* qws  = (unsigned short*)(ws + (12u << 20));        // 8 MB
  unsigned short* kws  = (unsigned short*)(ws + (20u << 20));        // 8 MB
  float*          sc   = (float*)        (ws + (28u << 20));         // 256 KB

  k_cast<<<(M1_ * H_ / 4 + 255) / 256, 256, 0, stream>>>((const float4*)lhs, lhsb, M1_ * H_ / 4);
  k_transW<<<dim3(N1_ / 32, H_ / 32), dim3(32, 8), 0, stream>>>(W, WT);
  k_sincos<<<(S_ * 32 + 255) / 256, 256, 0, stream>>>(sc);
  k_gemm1<<<dim3(N1_ / 128, M1_ / 128), 256, 0, stream>>>(lhsb, WT, bias, sc, qws, kws);
  k_gemm2<<<dim3(S_ / 128, S_ / 128, B_ * NH_), 256, 0, stream>>>(qws, kws, tl, out);
}

// Round 5
// 315.867 us; speedup vs baseline: 1.1919x; 1.0798x over previous
//
#include <hip/hip_runtime.h>
#include <hip/hip_bf16.h>
#include <stdint.h>

#define B_   4
#define S_   1024
#define H_   1024      // hidden
#define NH_  16        // ENT
#define D_   64        // INNER
#define N1_  2048      // ENT*2*INNER
#define M1_  4096      // B*S
#define NEG_ 1000000000000.0f

typedef __attribute__((ext_vector_type(8))) short bf16x8;
typedef __attribute__((ext_vector_type(4))) float f32x4;

__device__ inline void gload_lds16(const void* g, void* l) {
  __builtin_amdgcn_global_load_lds(
      (const __attribute__((address_space(1))) unsigned int*)g,
      (__attribute__((address_space(3))) unsigned int*)l, 16, 0, 0);
}

__device__ inline unsigned short f2bf(float f) {
  union { float f; uint32_t u; } a; a.f = f;
  uint32_t r = a.u + 0x7fff + ((a.u >> 16) & 1);   // RNE
  return (unsigned short)(r >> 16);
}

// ---------------- fused prep: cast + transW + sincos in one launch ----------------
// blocks [0,4096): cast lhs fp32->bf16 (1048576 float4s)
// blocks [4096,6144): transpose W (1024x2048 f32) -> WT (2048x1024 bf16)
// blocks [6144,6272): sin/cos table

__global__ __launch_bounds__(256) void k_prep(
    const float4* __restrict__ lhs4, unsigned short* __restrict__ lhsb,
    const float* __restrict__ W, unsigned short* __restrict__ WT,
    float* __restrict__ tab) {
  __shared__ float tsm[32][33];
  int b = blockIdx.x, t = threadIdx.x;
  if (b < 4096) {
    int i = b * 256 + t;          // < 1048576 always
    float4 v = lhs4[i];
    uint64_t pk = (uint64_t)f2bf(v.x) | ((uint64_t)f2bf(v.y) << 16) |
                  ((uint64_t)f2bf(v.z) << 32) | ((uint64_t)f2bf(v.w) << 48);
    ((uint64_t*)lhsb)[i] = pk;
  } else if (b < 6144) {
    int bb = b - 4096;            // 0..2047
    int nb = (bb & 63) * 32, kb = (bb >> 6) * 32;
    int tx = t & 31, ty = t >> 5; // (32,8)
    for (int r = 0; r < 4; r++)
      tsm[ty + r * 8][tx] = W[(size_t)(kb + ty + r * 8) * N1_ + nb + tx];
    __syncthreads();
    for (int r = 0; r < 4; r++)
      WT[(size_t)(nb + ty + r * 8) * H_ + kb + tx] = f2bf(tsm[tx][ty + r * 8]);
  } else {
    int i = (b - 6144) * 256 + t; // < 32768
    int pos = i >> 5, fi = i & 31;
    float freq = exp2f(-(float)fi * (13.2877123795494f / 32.0f)); // 10000^(-2fi/64)
    float ang = (float)pos * freq;
    tab[2 * i]     = sinf(ang);
    tab[2 * i + 1] = cosf(ang);
  }
}

// ---------------- stage 1: P = lhs @ W + b, fused RoPE, scatter to q/k ----------------
// Operand-swapped MFMA: n in register axis -> in-lane RoPE pairs, vector epilogue.
// XCD swizzle: each XCD owns 4 m-panels (A-panel fetched once per XCD set).

__global__ __launch_bounds__(256) void k_gemm1(
    const unsigned short* __restrict__ A,   // M1_ x H_ bf16
    const unsigned short* __restrict__ BT,  // N1_ x H_ bf16
    const float* __restrict__ bias,         // N1_
    const float* __restrict__ sc,           // sin/cos table
    unsigned short* __restrict__ qws,       // [B*NH][S][D] bf16
    unsigned short* __restrict__ kws) {
  __shared__ unsigned short a_lds[128 * 32];
  __shared__ unsigned short b_lds[128 * 32];
  int t = threadIdx.x;
  int lane = t & 63, wv = t >> 6;
  int wm = wv >> 1, wn = wv & 1;
  int col = lane & 15, quad = lane >> 4;

  // swizzle: l&7 = XCD; m-tile = (k&3)*8 + xcd; n-tile = k>>2
  int l = blockIdx.x;
  int xcd = l & 7, k = l >> 3;
  int mBase = (((k & 3) << 3) + xcd) * 128;   // 32 m-tiles
  int nBase = (k >> 2) * 128;                 // 16 n-tiles

  f32x4 acc[4][4] = {};   // [j: n-tile][i: m-tile]

  for (int kk = 0; kk < H_; kk += 32) {
    for (int c = 0; c < 2; c++) {
      int idx = c * 256 + t;
      int r = idx >> 2, ch = idx & 3;
      gload_lds16(A + (size_t)(mBase + r) * H_ + kk + ch * 8, a_lds + idx * 8);
      gload_lds16(BT + (size_t)(nBase + r) * H_ + kk + ch * 8, b_lds + idx * 8);
    }
    __syncthreads();
    bf16x8 af[4], bf[4];
#pragma unroll
    for (int i = 0; i < 4; i++)
      af[i] = *(const bf16x8*)&a_lds[(wm * 64 + i * 16 + col) * 32 + quad * 8];
#pragma unroll
    for (int j = 0; j < 4; j++)
      bf[j] = *(const bf16x8*)&b_lds[(wn * 64 + j * 16 + col) * 32 + quad * 8];
#pragma unroll
    for (int j = 0; j < 4; j++)
#pragma unroll
      for (int i = 0; i < 4; i++)
        acc[j][i] = __builtin_amdgcn_mfma_f32_16x16x32_bf16(bf[j], af[i], acc[j][i], 0, 0, 0);
    __syncthreads();
  }

  // epilogue: bias + interleaved RoPE (pairs in-lane) + ushort4 scatter
#pragma unroll
  for (int i = 0; i < 4; i++) {
    int m = mBase + wm * 64 + i * 16 + col;      // 0..4095
    int pos = m & (S_ - 1);
    int bb = m >> 10;
#pragma unroll
    for (int j = 0; j < 4; j++) {
      int n = nBase + wn * 64 + j * 16 + quad * 4;  // 4-aligned
      int d = n & 63;
      int head = n >> 7;
      int isK = (n >> 6) & 1;
      float4 bj  = *(const float4*)&bias[n];
      float4 scv = *(const float4*)&sc[(pos * 32 + (d >> 1)) * 2]; // s0,c0,s1,c1
      float v0 = acc[j][i][0] + bj.x;
      float v1 = acc[j][i][1] + bj.y;
      float v2 = acc[j][i][2] + bj.z;
      float v3 = acc[j][i][3] + bj.w;
      float o0 = v0 * scv.y - v1 * scv.x;
      float o1 = v1 * scv.y + v0 * scv.x;
      float o2 = v2 * scv.w - v3 * scv.z;
      float o3 = v3 * scv.w + v2 * scv.z;
      unsigned short* dst = isK ? kws : qws;
      ushort4 pk;
      pk.x = f2bf(o0); pk.y = f2bf(o1); pk.z = f2bf(o2); pk.w = f2bf(o3);
      *(ushort4*)&dst[((size_t)(bb * NH_ + head) * S_ + pos) * D_ + d] = pk;
    }
  }
}

// ---------------- stage 2: logits[b,h] = Q K^T with masks ----------------
// Operand-swapped MFMA + LDS-transposed epilogue + XCD z-locality swizzle
// (each XCD owns 8 whole heads -> Q/K panels fetched once per XCD) + NT stores.

#define STG_ 132   // stage row stride in floats (pad 4: float4-aligned, spreads banks)

__global__ __launch_bounds__(256) void k_gemm2(
    const unsigned short* __restrict__ qws,
    const unsigned short* __restrict__ kws,
    const float* __restrict__ tl,           // (B, S)
    float* __restrict__ out) {
  __shared__ __align__(16) char smem[64 * STG_ * 4];   // 33792 B >= 32768 B
  unsigned short* q_lds = (unsigned short*)smem;
  unsigned short* k_lds = q_lds + 128 * 64;
  float* stage = (float*)smem;

  int t = threadIdx.x;
  int lane = t & 63, wv = t >> 6, wm = wv >> 1, wn = wv & 1;
  int col = lane & 15, quad = lane >> 4;

  // swizzle: l&7 = XCD; z = xcd*8 + (k>>6); tile = k&63
  int l = blockIdx.x;                 // 0..4095
  int xcd = l & 7, k = l >> 3;        // k: 0..511
  int z = (xcd << 3) + (k >> 6);      // 0..63 (b*16+h)
  int tile = k & 63;
  int mT = (tile >> 3) * 128, nT = (tile & 7) * 128;

  const unsigned short* qb = qws + ((size_t)z * S_ + mT) * D_;  // contiguous 16KB
  const unsigned short* kb = kws + ((size_t)z * S_ + nT) * D_;

  for (int c = 0; c < 4; c++) {
    int idx = c * 256 + t;
    gload_lds16(qb + idx * 8, q_lds + idx * 8);
    gload_lds16(kb + idx * 8, k_lds + idx * 8);
  }
  __syncthreads();

  f32x4 acc[4][4] = {};   // [j: n-tile][i: m-tile]
#pragma unroll
  for (int kk = 0; kk < 64; kk += 32) {
    bf16x8 qf[4], kf[4];
#pragma unroll
    for (int i = 0; i < 4; i++)
      qf[i] = *(const bf16x8*)&q_lds[(wm * 64 + i * 16 + col) * 64 + kk + quad * 8];
#pragma unroll
    for (int j = 0; j < 4; j++)
      kf[j] = *(const bf16x8*)&k_lds[(wn * 64 + j * 16 + col) * 64 + kk + quad * 8];
#pragma unroll
    for (int j = 0; j < 4; j++)
#pragma unroll
      for (int i = 0; i < 4; i++)
        acc[j][i] = __builtin_amdgcn_mfma_f32_16x16x32_bf16(kf[j], qf[i], acc[j][i], 0, 0, 0);
  }
  __syncthreads();   // everyone done reading q_lds/k_lds before stage overwrite

  int bb = z >> 4;
#pragma unroll
  for (int half = 0; half < 2; half++) {
    if (wm == half) {
#pragma unroll
      for (int i = 0; i < 4; i++) {
        int rloc = i * 16 + col;
#pragma unroll
        for (int j = 0; j < 4; j++) {
          int cloc = wn * 64 + j * 16 + quad * 4;
          float4 v;
          v.x = acc[j][i][0]; v.y = acc[j][i][1];
          v.z = acc[j][i][2]; v.w = acc[j][i][3];
          *(float4*)&stage[rloc * STG_ + cloc] = v;
        }
      }
    }
    __syncthreads();
    // all 256 threads: store 64 rows x 128 cols, fully coalesced, non-temporal
    int mbase = mT + half * 64;
#pragma unroll
    for (int r = 0; r < 8; r++) {
      int f = r * 256 + t;        // 0..2047
      int rloc = f >> 5;          // 0..63
      int c4 = (f & 31) * 4;      // 0..124
      float4 v = *(const float4*)&stage[rloc * STG_ + c4];
      int m = mbase + rloc;
      int n = nT + c4;
      float4 pad4 = *(const float4*)&tl[bb * S_ + n];
      f32x4 o;
      float x;
      x = v.x * pad4.x - (1.0f - pad4.x) * NEG_; if (m > n)     x -= NEG_; o.x = x * 0.125f;
      x = v.y * pad4.y - (1.0f - pad4.y) * NEG_; if (m > n + 1) x -= NEG_; o.y = x * 0.125f;
      x = v.z * pad4.z - (1.0f - pad4.z) * NEG_; if (m > n + 2) x -= NEG_; o.z = x * 0.125f;
      x = v.w * pad4.w - (1.0f - pad4.w) * NEG_; if (m > n + 3) x -= NEG_; o.w = x * 0.125f;
      __builtin_nontemporal_store(o, (f32x4*)&out[((size_t)z * S_ + m) * S_ + n]);
    }
    __syncthreads();   // protect stage before next half's writes
  }
}

// ---------------- launch ----------------

extern "C" void kernel_launch(void* const* d_in, const int* in_sizes, int n_in,
                              void* d_out, int out_size, void* d_ws, size_t ws_size,
                              hipStream_t stream) {
  const float* lhs  = (const float*)d_in[0];   // (4,1024,1024)
  const float* W    = (const float*)d_in[1];   // (1024,2048)
  const float* bias = (const float*)d_in[2];   // (2048,)
  const float* tl   = (const float*)d_in[3];   // (4,1024)
  float* out = (float*)d_out;

  char* ws = (char*)d_ws;
  unsigned short* lhsb = (unsigned short*)(ws);                      // 8 MB
  unsigned short* WT   = (unsigned short*)(ws + (8u  << 20));        // 4 MB
  unsigned short* qws  = (unsigned short*)(ws + (12u << 20));        // 8 MB
  unsigned short* kws  = (unsigned short*)(ws + (20u << 20));        // 8 MB
  float*          sc   = (float*)        (ws + (28u << 20));         // 256 KB

  k_prep<<<6272, 256, 0, stream>>>((const float4*)lhs, lhsb, W, WT, sc);
  k_gemm1<<<512, 256, 0, stream>>>(lhsb, WT, bias, sc, qws, kws);
  k_gemm2<<<4096, 256, 0, stream>>>(qws, kws, tl, out);
}